// Round 13
// baseline (215.339 us; speedup 1.0000x reference)
//
#include <hip/hip_runtime.h>

#define N_NODES 50000
#define E_EDGES 800000
#define EA (E_EDGES + N_NODES)   // 850000 edges incl self loops
#define NG 128                   // num graphs
#define NEG 0.2f
#define NB_SCAN ((N_NODES + 255) / 256)   // 196 scan blocks
#define PCH 64                   // pool rows per block

typedef _Float16 half8  __attribute__((ext_vector_type(8)));
typedef _Float16 half2t __attribute__((ext_vector_type(2)));
typedef float    floatx4 __attribute__((ext_vector_type(4)));

__device__ __forceinline__ half2t h2bits(unsigned u) { return __builtin_bit_cast(half2t, u); }

// ---------------- init: zero deg + pool sums + W transpose/convert + alpha columns ----------------
__global__ void init_kernel(const float* __restrict__ W0, const float* __restrict__ W1,
                            const float* __restrict__ as0, const float* __restrict__ ad0,
                            const float* __restrict__ as1, const float* __restrict__ ad1,
                            _Float16* __restrict__ Wt0, _Float16* __restrict__ Wt1,
                            int* __restrict__ deg, float* __restrict__ sums) {
    int i = blockIdx.x * 256 + threadIdx.x;
    if (i < N_NODES) deg[i] = 0;
    if (i < NG * 128) sums[i] = 0.f;
    if (i < 16384) {
        int c = i >> 7, k = i & 127;
        Wt0[c * 128 + k] = (_Float16)W0[k * 128 + c];
        Wt1[c * 128 + k] = (_Float16)W1[k * 128 + c];
    }
    if (i >= 16384 && i < 16640) {
        int j = i - 16384;
        const float* W  = (j & 128) ? W1  : W0;
        const float* as_ = (j & 128) ? as1 : as0;
        const float* ad_ = (j & 128) ? ad1 : ad0;
        _Float16* Wt = (j & 128) ? Wt1 : Wt0;
        int k = j & 127;
        float s0 = 0.f, s1 = 0.f, d0 = 0.f, d1 = 0.f;
        for (int c = 0; c < 64; ++c) {
            float w0v = W[k * 128 + c], w1v = W[k * 128 + 64 + c];
            s0 += w0v * as_[c]; s1 += w1v * as_[64 + c];
            d0 += w0v * ad_[c]; d1 += w1v * ad_[64 + c];
        }
        Wt[(128 + 0) * 128 + k] = (_Float16)s0;
        Wt[(128 + 1) * 128 + k] = (_Float16)s1;
        Wt[(128 + 2) * 128 + k] = (_Float16)d0;
        Wt[(128 + 3) * 128 + k] = (_Float16)d1;
    }
}

// ---------------- CSR build ----------------
__global__ void hist_kernel(const int* __restrict__ ei, int* __restrict__ deg,
                            int* __restrict__ rank) {
    int e = blockIdx.x * blockDim.x + threadIdx.x;
    if (e >= EA) return;
    int d = (e < E_EDGES) ? ei[E_EDGES + e] : (e - E_EDGES);
    rank[e] = atomicAdd(&deg[d], 1);
}

__global__ void partial_kernel(const int* __restrict__ deg, int* __restrict__ part) {
    __shared__ int buf[4];
    int i = blockIdx.x * 256 + threadIdx.x;
    int v = (i < N_NODES) ? deg[i] : 0;
    for (int o = 32; o; o >>= 1) v += __shfl_xor(v, o);
    if ((threadIdx.x & 63) == 0) buf[threadIdx.x >> 6] = v;
    __syncthreads();
    if (threadIdx.x == 0) part[blockIdx.x] = buf[0] + buf[1] + buf[2] + buf[3];
}

// fused: block offset from self-scanned partials + local exclusive scan
__global__ void rowstart_kernel(const int* __restrict__ deg, const int* __restrict__ part,
                                int* __restrict__ rowstart) {
    __shared__ int buf[256];
    __shared__ int wsum[4];
    __shared__ int offs;
    int t = threadIdx.x;
    int pv = (t < blockIdx.x) ? part[t] : 0;
    for (int o = 32; o; o >>= 1) pv += __shfl_xor(pv, o);
    if ((t & 63) == 0) wsum[t >> 6] = pv;
    __syncthreads();
    if (t == 0) offs = wsum[0] + wsum[1] + wsum[2] + wsum[3];
    int i = blockIdx.x * 256 + t;
    int v = (i < N_NODES) ? deg[i] : 0;
    buf[t] = v;
    __syncthreads();
    for (int o = 1; o < 256; o <<= 1) {
        int u = (t >= o) ? buf[t - o] : 0;
        __syncthreads();
        buf[t] += u;
        __syncthreads();
    }
    if (i < N_NODES) rowstart[i] = offs + buf[t] - v;
    if (i == N_NODES - 1) rowstart[N_NODES] = offs + buf[t];
}

// atomic-free scatter of resolved (src, nq) payload
__global__ void build_kernel(const int* __restrict__ ei, const float* __restrict__ ec,
                             const float* __restrict__ nc, const int* __restrict__ rowstart,
                             const int* __restrict__ rank, uint2* __restrict__ csr2) {
    int e = blockIdx.x * blockDim.x + threadIdx.x;
    if (e >= EA) return;
    int s, d; float nq;
    if (e < E_EDGES) { s = ei[e]; d = ei[E_EDGES + e]; nq = ec[e]; }
    else             { s = e - E_EDGES; d = s; nq = nc[s]; }
    csr2[rowstart[d] + rank[e]] = make_uint2((unsigned)s, __float_as_uint(nq));
}

// ---------------- MFMA GEMM; alpha = 4 extra output columns (wave 0) ----------------
template<int SRC_F32>
__global__ __launch_bounds__(256) void gemm_mfma(const void* __restrict__ Xsrc,
                                                 const _Float16* __restrict__ Wt,   // 132 x 128
                                                 unsigned* __restrict__ Hb,   // fp16-packed H
                                                 float* __restrict__ als,
                                                 float* __restrict__ ald) {
    __shared__ _Float16 As[64][136];      // padded; reused as fp16 store-stage
    __shared__ _Float16 Bs[128 * 128];    // XOR-swizzled 8-elem groups
    __shared__ _Float16 Bs_a[4][136];     // alpha columns wa0,wa1,wd0,wd1
    const int tid = threadIdx.x;
    const int row0 = blockIdx.x * 64;

    if (SRC_F32) {
        const float* X = (const float*)Xsrc;
        for (int i = 0; i < 8; ++i) {
            int idx = tid + i * 256;
            int r = idx >> 5, q = idx & 31;
            int gr = row0 + r;
            float4 v = make_float4(0.f, 0.f, 0.f, 0.f);
            if (gr < N_NODES) v = ((const float4*)X)[(size_t)gr * 32 + q];
            half2t p0 = { (_Float16)v.x, (_Float16)v.y };
            half2t p1 = { (_Float16)v.z, (_Float16)v.w };
            *(half2t*)&As[r][q * 4]     = p0;
            *(half2t*)&As[r][q * 4 + 2] = p1;
        }
    } else {
        const uint4* X = (const uint4*)Xsrc;
        for (int i = 0; i < 4; ++i) {
            int idx = tid + i * 256;
            int r = idx >> 4, q = idx & 15;
            int gr = row0 + r;
            uint4 v = make_uint4(0u, 0u, 0u, 0u);
            if (gr < N_NODES) v = X[(size_t)gr * 16 + q];
            *(uint4*)&As[r][q * 8] = v;
        }
    }
    for (int i = 0; i < 8; ++i) {
        int idx = tid + i * 256;
        int r = idx >> 4, q = idx & 15;
        *(uint4*)&Bs[r * 128 + ((q ^ (r & 15)) << 3)] = ((const uint4*)Wt)[r * 16 + q];
    }
    if (tid < 64) {
        int r = tid >> 4, q = tid & 15;
        *(uint4*)&Bs_a[r][q * 8] = ((const uint4*)Wt)[(128 + r) * 16 + q];
    }
    __syncthreads();

    const int l = tid & 63, wv = tid >> 6;
    const int c0w = wv * 32;
    const int lr = l & 15, lq = l >> 4;

    floatx4 acc[4][2];
    floatx4 acc_a[4];
#pragma unroll
    for (int m = 0; m < 4; ++m) {
#pragma unroll
        for (int n = 0; n < 2; ++n) acc[m][n] = (floatx4){0.f, 0.f, 0.f, 0.f};
        acc_a[m] = (floatx4){0.f, 0.f, 0.f, 0.f};
    }

#pragma unroll
    for (int kk = 0; kk < 4; ++kk) {
        int kb = kk * 32 + lq * 8;
        int kg = (kk * 4 + lq) ^ lr;
        half8 a0 = *(const half8*)&As[lr][kb];
        half8 a1 = *(const half8*)&As[16 + lr][kb];
        half8 a2 = *(const half8*)&As[32 + lr][kb];
        half8 a3 = *(const half8*)&As[48 + lr][kb];
        half8 b0 = *(const half8*)&Bs[(c0w + lr) * 128 + (kg << 3)];
        half8 b1 = *(const half8*)&Bs[(c0w + 16 + lr) * 128 + (kg << 3)];
        acc[0][0] = __builtin_amdgcn_mfma_f32_16x16x32_f16(a0, b0, acc[0][0], 0, 0, 0);
        acc[1][0] = __builtin_amdgcn_mfma_f32_16x16x32_f16(a1, b0, acc[1][0], 0, 0, 0);
        acc[2][0] = __builtin_amdgcn_mfma_f32_16x16x32_f16(a2, b0, acc[2][0], 0, 0, 0);
        acc[3][0] = __builtin_amdgcn_mfma_f32_16x16x32_f16(a3, b0, acc[3][0], 0, 0, 0);
        acc[0][1] = __builtin_amdgcn_mfma_f32_16x16x32_f16(a0, b1, acc[0][1], 0, 0, 0);
        acc[1][1] = __builtin_amdgcn_mfma_f32_16x16x32_f16(a1, b1, acc[1][1], 0, 0, 0);
        acc[2][1] = __builtin_amdgcn_mfma_f32_16x16x32_f16(a2, b1, acc[2][1], 0, 0, 0);
        acc[3][1] = __builtin_amdgcn_mfma_f32_16x16x32_f16(a3, b1, acc[3][1], 0, 0, 0);
        if (wv == 0) {
            half8 ba = (lr < 4) ? *(const half8*)&Bs_a[lr & 3][kb]
                                : (half8){0, 0, 0, 0, 0, 0, 0, 0};
            acc_a[0] = __builtin_amdgcn_mfma_f32_16x16x32_f16(a0, ba, acc_a[0], 0, 0, 0);
            acc_a[1] = __builtin_amdgcn_mfma_f32_16x16x32_f16(a1, ba, acc_a[1], 0, 0, 0);
            acc_a[2] = __builtin_amdgcn_mfma_f32_16x16x32_f16(a2, ba, acc_a[2], 0, 0, 0);
            acc_a[3] = __builtin_amdgcn_mfma_f32_16x16x32_f16(a3, ba, acc_a[3], 0, 0, 0);
        }
    }

    __syncthreads();   // reuse As as store stage

#pragma unroll
    for (int m = 0; m < 4; ++m) {
#pragma unroll
        for (int reg = 0; reg < 4; ++reg) {
            int rl = 16 * m + 4 * lq + reg;
            _Float16* rowp = &As[rl][0];
            rowp[c0w + lr]      = (_Float16)acc[m][0][reg];
            rowp[c0w + 16 + lr] = (_Float16)acc[m][1][reg];
        }
    }
    __syncthreads();

    for (int i = 0; i < 4; ++i) {
        int idx = tid + i * 256;
        int r = idx >> 4, q = idx & 15;
        int grow = row0 + r;
        if (grow < N_NODES) {
            uint4 v = *(uint4*)((unsigned short*)&As[r][0] + q * 8);
            ((uint4*)Hb)[(size_t)grow * 16 + q] = v;
        }
    }
    if (wv == 0 && lr < 4) {
#pragma unroll
        for (int m = 0; m < 4; ++m) {
#pragma unroll
            for (int reg = 0; reg < 4; ++reg) {
                int grow = row0 + 16 * m + 4 * lq + reg;
                if (grow < N_NODES) {
                    float v = acc_a[m][reg];
                    if (lr == 0)      als[grow * 2 + 0] = v;
                    else if (lr == 1) als[grow * 2 + 1] = v;
                    else if (lr == 2) ald[grow * 2 + 0] = v;
                    else              ald[grow * 2 + 1] = v;
                }
            }
        }
    }
}

// ---------------- per-node softmax + aggregation: 64-thread blocks, 2 nodes per wave ----------------
// One wave per block (finest scheduling granularity). lanes 0-31 own node n0, 32-63 own n1.
__global__ __launch_bounds__(64) void agg_kernel(const uint4* __restrict__ Hb4,
                                                 const uint2* __restrict__ csr2,
                                                 const float* __restrict__ als,
                                                 const float* __restrict__ ald,
                                                 const int* __restrict__ rowstart,
                                                 const float* __restrict__ bias,
                                                 _Float16* __restrict__ outp) {
    __shared__ uint4 sw[64];             // [hl*32 + j]
    const int lane = threadIdx.x;        // 0..63
    const int hl   = lane >> 5;          // node slot within wave
    const int l32  = lane & 31;
    const int n = blockIdx.x * 2 + hl;   // N_NODES = 50000 = 25000*2 exactly

    int start = rowstart[n], end = rowstart[n + 1];
    int deg = end - start;
    const float2* als2 = (const float2*)als;
    float2 adn = ((const float2*)ald)[n];

    // l32 j resolves edge j (covers deg<=32, i.e. essentially every node)
    int   s_reg  = n;
    float nq_reg = 0.f, a0_reg = -1e30f, a1_reg = -1e30f;
    if (l32 < deg) {
        uint2 v = csr2[start + l32];
        s_reg  = (int)v.x;
        nq_reg = __uint_as_float(v.y);
        float2 av = als2[s_reg];
        float a0 = av.x + adn.x; a0_reg = (a0 > 0.f) ? a0 : NEG * a0;
        float a1 = av.y + adn.y; a1_reg = (a1 > 0.f) ? a1 : NEG * a1;
    }
    // per-node max (rare stride loop for deg>32)
    float m0 = a0_reg, m1 = a1_reg;
    for (int i = start + 32 + l32; i < end; i += 32) {
        uint2 v = csr2[i];
        float2 av = als2[v.x];
        float a0 = av.x + adn.x; a0 = (a0 > 0.f) ? a0 : NEG * a0;
        float a1 = av.y + adn.y; a1 = (a1 > 0.f) ? a1 : NEG * a1;
        m0 = fmaxf(m0, a0); m1 = fmaxf(m1, a1);
    }
    for (int o = 16; o; o >>= 1) { m0 = fmaxf(m0, __shfl_xor(m0, o)); m1 = fmaxf(m1, __shfl_xor(m1, o)); }

    float e0 = __expf(a0_reg - m0), e1 = __expf(a1_reg - m1);
    float s0 = e0, s1 = e1;
    for (int i = start + 32 + l32; i < end; i += 32) {
        uint2 v = csr2[i];
        float2 av = als2[v.x];
        float a0 = av.x + adn.x; a0 = (a0 > 0.f) ? a0 : NEG * a0;
        float a1 = av.y + adn.y; a1 = (a1 > 0.f) ? a1 : NEG * a1;
        s0 += __expf(a0 - m0); s1 += __expf(a1 - m1);
    }
    for (int o = 16; o; o >>= 1) { s0 += __shfl_xor(s0, o); s1 += __shfl_xor(s1, o); }
    float inv0 = 1.f / (s0 + 1e-16f), inv1 = 1.f / (s1 + 1e-16f);

    // stash (s, w0, w1); lanes >= deg have nq_reg=0 -> w=0, s=n (safe row)
    sw[hl * 32 + l32] = make_uint4((unsigned)s_reg,
                                   __float_as_uint(nq_reg * e0 * inv0),
                                   __float_as_uint(nq_reg * e1 * inv1), 0u);

    const int  c16   = l32 & 15;       // uint4 column: channels 8*c16 .. 8*c16+7
    const int  g     = l32 >> 4;       // edge subgroup within node
    const bool head0 = (c16 < 8);
    float acc0 = 0.f, acc1 = 0.f, acc2 = 0.f, acc3 = 0.f;
    float acc4 = 0.f, acc5 = 0.f, acc6 = 0.f, acc7 = 0.f;
    int cnt2 = (deg < 32) ? ((deg + 1) & ~1) : 32;
#pragma unroll 16
    for (int jp = 0; jp < cnt2; jp += 2) {
        uint4 sv = sw[hl * 32 + jp + g];
        float w  = __uint_as_float(head0 ? sv.y : sv.z);
        uint4 hv = Hb4[(size_t)(sv.x * 16u + (unsigned)c16)];
        half2t h0 = h2bits(hv.x), h1 = h2bits(hv.y), h2 = h2bits(hv.z), h3 = h2bits(hv.w);
        acc0 += (float)h0.x * w; acc1 += (float)h0.y * w;
        acc2 += (float)h1.x * w; acc3 += (float)h1.y * w;
        acc4 += (float)h2.x * w; acc5 += (float)h2.y * w;
        acc6 += (float)h3.x * w; acc7 += (float)h3.y * w;
    }
    // rare deg>32: process remaining chunks of 32 (per-half divergence is fine)
    for (int cbase = start + 32; cbase < end; cbase += 32) {
        int   s2 = n; float w0f = 0.f, w1f = 0.f;
        int i = cbase + l32;
        if (i < end) {
            uint2 v = csr2[i];
            s2 = (int)v.x;
            float nq = __uint_as_float(v.y);
            float2 av = als2[s2];
            float a0 = av.x + adn.x; a0 = (a0 > 0.f) ? a0 : NEG * a0;
            float a1 = av.y + adn.y; a1 = (a1 > 0.f) ? a1 : NEG * a1;
            w0f = nq * __expf(a0 - m0) * inv0;
            w1f = nq * __expf(a1 - m1) * inv1;
        }
        sw[hl * 32 + l32] = make_uint4((unsigned)s2, __float_as_uint(w0f),
                                       __float_as_uint(w1f), 0u);
        int rem = end - cbase; if (rem > 32) rem = 32;
        int r2 = (rem + 1) & ~1;
        for (int jp = 0; jp < r2; jp += 2) {
            uint4 sv = sw[hl * 32 + jp + g];
            float w  = __uint_as_float(head0 ? sv.y : sv.z);
            uint4 hv = Hb4[(size_t)(sv.x * 16u + (unsigned)c16)];
            half2t h0 = h2bits(hv.x), h1 = h2bits(hv.y), h2 = h2bits(hv.z), h3 = h2bits(hv.w);
            acc0 += (float)h0.x * w; acc1 += (float)h0.y * w;
            acc2 += (float)h1.x * w; acc3 += (float)h1.y * w;
            acc4 += (float)h2.x * w; acc5 += (float)h2.y * w;
            acc6 += (float)h3.x * w; acc7 += (float)h3.y * w;
        }
    }
    // combine the 2 edge subgroups (within the half)
    acc0 += __shfl_xor(acc0, 16); acc1 += __shfl_xor(acc1, 16);
    acc2 += __shfl_xor(acc2, 16); acc3 += __shfl_xor(acc3, 16);
    acc4 += __shfl_xor(acc4, 16); acc5 += __shfl_xor(acc5, 16);
    acc6 += __shfl_xor(acc6, 16); acc7 += __shfl_xor(acc7, 16);

    if (g == 0) {
        float4 ba = ((const float4*)bias)[c16 * 2];
        float4 bb = ((const float4*)bias)[c16 * 2 + 1];
        float o0 = acc0 + ba.x; o0 = o0 > 0.f ? o0 : 0.f;
        float o1 = acc1 + ba.y; o1 = o1 > 0.f ? o1 : 0.f;
        float o2 = acc2 + ba.z; o2 = o2 > 0.f ? o2 : 0.f;
        float o3 = acc3 + ba.w; o3 = o3 > 0.f ? o3 : 0.f;
        float o4 = acc4 + bb.x; o4 = o4 > 0.f ? o4 : 0.f;
        float o5 = acc5 + bb.y; o5 = o5 > 0.f ? o5 : 0.f;
        float o6 = acc6 + bb.z; o6 = o6 > 0.f ? o6 : 0.f;
        float o7 = acc7 + bb.w; o7 = o7 > 0.f ? o7 : 0.f;
        half8 hv = { (_Float16)o0, (_Float16)o1, (_Float16)o2, (_Float16)o3,
                     (_Float16)o4, (_Float16)o5, (_Float16)o6, (_Float16)o7 };
        *(half8*)(outp + (size_t)n * 128 + 8 * c16) = hv;
    }
}

// ---------------- global mean pool: chunked partial sums + atomics ----------------
__global__ __launch_bounds__(256) void pool_partial(const half2t* __restrict__ Obh,
                                                    const int* __restrict__ batch,
                                                    float* __restrict__ sums) {
    int row0 = blockIdx.x * PCH;
    int c2 = threadIdx.x & 63;   // half2 column: channels 2c2, 2c2+1
    int r4 = threadIdx.x >> 6;   // 0..3 row phase
    int end = row0 + PCH; if (end > N_NODES) end = N_NODES;
    float a0 = 0.f, a1 = 0.f;
    int curg = -1;
    for (int i = row0 + r4; i < end; i += 4) {
        int g = batch[i];
        if (g != curg) {
            if (curg >= 0) {
                atomicAdd(&sums[curg * 128 + 2 * c2],     a0);
                atomicAdd(&sums[curg * 128 + 2 * c2 + 1], a1);
            }
            a0 = 0.f; a1 = 0.f; curg = g;
        }
        half2t hv = Obh[(size_t)i * 64 + c2];
        a0 += (float)hv.x;
        a1 += (float)hv.y;
    }
    if (curg >= 0) {
        atomicAdd(&sums[curg * 128 + 2 * c2],     a0);
        atomicAdd(&sums[curg * 128 + 2 * c2 + 1], a1);
    }
}

// ---------------- classifier: (sums/cnt) @ Wc + bc ----------------
__global__ void cls_kernel(const float* __restrict__ sums, const int* __restrict__ batch,
                           const float* __restrict__ Wc, const float* __restrict__ bc,
                           float* __restrict__ outp) {
    int g = blockIdx.x;
    __shared__ float p[128];
    __shared__ int cnt_s;
    if (threadIdx.x == 0) {
        int lo = 0, hi = N_NODES;
        while (lo < hi) { int mid = (lo + hi) >> 1; if (batch[mid] < g) lo = mid + 1; else hi = mid; }
        int start = lo;
        hi = N_NODES;
        while (lo < hi) { int mid = (lo + hi) >> 1; if (batch[mid] <= g) lo = mid + 1; else hi = mid; }
        cnt_s = lo - start;
    }
    __syncthreads();
    float inv = 1.f / fmaxf((float)cnt_s, 1.f);
    p[threadIdx.x] = sums[g * 128 + threadIdx.x] * inv;
    __syncthreads();
    if (threadIdx.x < 10) {
        float acc = bc[threadIdx.x];
        for (int k = 0; k < 128; ++k) acc += p[k] * Wc[k * 10 + threadIdx.x];
        outp[g * 10 + threadIdx.x] = acc;
    }
}

extern "C" void kernel_launch(void* const* d_in, const int* in_sizes, int n_in,
                              void* d_out, int out_size, void* d_ws, size_t ws_size,
                              hipStream_t stream) {
    const float* x     = (const float*)d_in[0];
    const int*   ei    = (const int*)d_in[1];
    const int*   batch = (const int*)d_in[2];
    const float* nc    = (const float*)d_in[3];
    const float* ec    = (const float*)d_in[4];
    const float* W0    = (const float*)d_in[5];
    const float* as0   = (const float*)d_in[6];
    const float* ad0   = (const float*)d_in[7];
    const float* b0    = (const float*)d_in[8];
    const float* W1    = (const float*)d_in[9];
    const float* as1   = (const float*)d_in[10];
    const float* ad1   = (const float*)d_in[11];
    const float* b1    = (const float*)d_in[12];
    const float* Wc    = (const float*)d_in[13];
    const float* bc    = (const float*)d_in[14];
    float* out = (float*)d_out;

    char* ws = (char*)d_ws;
    size_t off = 0;
    auto alloc = [&](size_t bytes) { void* p = ws + off; off += (bytes + 255) & ~size_t(255); return p; };
    unsigned*  Hb       = (unsigned*)alloc(sizeof(unsigned) * N_NODES * 64);    // fp16 H (pre-attn)
    _Float16*  Xh       = (_Float16*)alloc(sizeof(_Float16) * N_NODES * 128);   // fp16 layer-1 input
    _Float16*  Ob       = (_Float16*)alloc(sizeof(_Float16) * N_NODES * 128);   // fp16 layer-1 output
    float*     als      = (float*)alloc(sizeof(float) * N_NODES * 2);
    float*     ald      = (float*)alloc(sizeof(float) * N_NODES * 2);
    _Float16*  Wt0      = (_Float16*)alloc(sizeof(_Float16) * 132 * 128);       // +4 alpha rows
    _Float16*  Wt1      = (_Float16*)alloc(sizeof(_Float16) * 132 * 128);
    int*       deg      = (int*)alloc(sizeof(int) * N_NODES);
    int*       rank     = (int*)alloc(sizeof(int) * EA);
    int*       part     = (int*)alloc(sizeof(int) * NB_SCAN);
    int*       rowstart = (int*)alloc(sizeof(int) * (N_NODES + 1));
    uint2*     csr2     = (uint2*)alloc(sizeof(uint2) * EA);
    float*     sums     = (float*)alloc(sizeof(float) * NG * 128);

    init_kernel<<<NB_SCAN, 256, 0, stream>>>(W0, W1, as0, ad0, as1, ad1, Wt0, Wt1, deg, sums);
    hist_kernel<<<(EA + 255) / 256, 256, 0, stream>>>(ei, deg, rank);
    partial_kernel<<<NB_SCAN, 256, 0, stream>>>(deg, part);
    rowstart_kernel<<<NB_SCAN, 256, 0, stream>>>(deg, part, rowstart);
    build_kernel<<<(EA + 255) / 256, 256, 0, stream>>>(ei, ec, nc, rowstart, rank, csr2);

    int gemm_grid  = (N_NODES + 63) / 64;            // 782
    int agg_blocks = N_NODES / 2;                    // 25000 (2 nodes per 1-wave block)

    // layer 0
    gemm_mfma<1><<<gemm_grid, 256, 0, stream>>>(x, Wt0, Hb, als, ald);
    agg_kernel<<<agg_blocks, 64, 0, stream>>>((const uint4*)Hb, csr2, als, ald, rowstart, b0, Xh);

    // layer 1
    gemm_mfma<0><<<gemm_grid, 256, 0, stream>>>(Xh, Wt1, Hb, als, ald);
    agg_kernel<<<agg_blocks, 64, 0, stream>>>((const uint4*)Hb, csr2, als, ald, rowstart, b1, Ob);

    // pool (chunked partials) + classifier
    pool_partial<<<(N_NODES + PCH - 1) / PCH, 256, 0, stream>>>((const half2t*)Ob, batch, sums);
    cls_kernel<<<NG, 128, 0, stream>>>(sums, batch, Wc, bc, out);
}

// Round 14
// 197.790 us; speedup vs baseline: 1.0887x; 1.0887x over previous
//
#include <hip/hip_runtime.h>

#define N_NODES 50000
#define E_EDGES 800000
#define EA (E_EDGES + N_NODES)   // 850000 edges incl self loops
#define NG 128                   // num graphs
#define NEG 0.2f
#define NB_SCAN ((N_NODES + 255) / 256)   // 196 scan blocks
#define PCH 64                   // pool rows per block

typedef _Float16 half8  __attribute__((ext_vector_type(8)));
typedef _Float16 half2t __attribute__((ext_vector_type(2)));
typedef float    floatx4 __attribute__((ext_vector_type(4)));

__device__ __forceinline__ half2t h2bits(unsigned u) { return __builtin_bit_cast(half2t, u); }

// ---------------- init: zero deg + pool sums + W transpose/convert ----------------
__global__ void init_kernel(const float* __restrict__ W0, const float* __restrict__ W1,
                            _Float16* __restrict__ Wt0, _Float16* __restrict__ Wt1,
                            int* __restrict__ deg, float* __restrict__ sums) {
    int i = blockIdx.x * 256 + threadIdx.x;
    if (i < N_NODES) deg[i] = 0;
    if (i < NG * 128) sums[i] = 0.f;
    if (i < 16384) {
        int c = i >> 7, k = i & 127;
        Wt0[c * 128 + k] = (_Float16)W0[k * 128 + c];
        Wt1[c * 128 + k] = (_Float16)W1[k * 128 + c];
    }
}

// ---------------- CSR build ----------------
__global__ void hist_kernel(const int* __restrict__ ei, int* __restrict__ deg,
                            int* __restrict__ rank) {
    int e = blockIdx.x * blockDim.x + threadIdx.x;
    if (e >= EA) return;
    int d = (e < E_EDGES) ? ei[E_EDGES + e] : (e - E_EDGES);
    rank[e] = atomicAdd(&deg[d], 1);
}

__global__ void partial_kernel(const int* __restrict__ deg, int* __restrict__ part) {
    __shared__ int buf[4];
    int i = blockIdx.x * 256 + threadIdx.x;
    int v = (i < N_NODES) ? deg[i] : 0;
    for (int o = 32; o; o >>= 1) v += __shfl_xor(v, o);
    if ((threadIdx.x & 63) == 0) buf[threadIdx.x >> 6] = v;
    __syncthreads();
    if (threadIdx.x == 0) part[blockIdx.x] = buf[0] + buf[1] + buf[2] + buf[3];
}

// fused: block offset from self-scanned partials + local exclusive scan
__global__ void rowstart_kernel(const int* __restrict__ deg, const int* __restrict__ part,
                                int* __restrict__ rowstart) {
    __shared__ int buf[256];
    __shared__ int wsum[4];
    __shared__ int offs;
    int t = threadIdx.x;
    int pv = (t < blockIdx.x) ? part[t] : 0;
    for (int o = 32; o; o >>= 1) pv += __shfl_xor(pv, o);
    if ((t & 63) == 0) wsum[t >> 6] = pv;
    __syncthreads();
    if (t == 0) offs = wsum[0] + wsum[1] + wsum[2] + wsum[3];
    int i = blockIdx.x * 256 + t;
    int v = (i < N_NODES) ? deg[i] : 0;
    buf[t] = v;
    __syncthreads();
    for (int o = 1; o < 256; o <<= 1) {
        int u = (t >= o) ? buf[t - o] : 0;
        __syncthreads();
        buf[t] += u;
        __syncthreads();
    }
    if (i < N_NODES) rowstart[i] = offs + buf[t] - v;
    if (i == N_NODES - 1) rowstart[N_NODES] = offs + buf[t];
}

// atomic-free scatter of resolved (src, nq) payload
__global__ void build_kernel(const int* __restrict__ ei, const float* __restrict__ ec,
                             const float* __restrict__ nc, const int* __restrict__ rowstart,
                             const int* __restrict__ rank, uint2* __restrict__ csr2) {
    int e = blockIdx.x * blockDim.x + threadIdx.x;
    if (e >= EA) return;
    int s, d; float nq;
    if (e < E_EDGES) { s = ei[e]; d = ei[E_EDGES + e]; nq = ec[e]; }
    else             { s = e - E_EDGES; d = s; nq = nc[s]; }
    csr2[rowstart[d] + rank[e]] = make_uint2((unsigned)s, __float_as_uint(nq));
}

// ---------------- MFMA GEMM + fused alpha ----------------
// block: 256 threads (4 waves), tile 64 rows x 128 cols, K=128.
// A-frag: row = l&15, k = (l>>4)*8+j.  C/D: col = l&15, row = (l>>4)*4+reg.
template<int SRC_F32>
__global__ __launch_bounds__(256) void gemm_mfma(const void* __restrict__ Xsrc,
                                                 const _Float16* __restrict__ Wt,
                                                 const float* __restrict__ as_,
                                                 const float* __restrict__ ad_,
                                                 unsigned* __restrict__ Hb,   // fp16-packed H
                                                 float* __restrict__ als,
                                                 float* __restrict__ ald) {
    __shared__ _Float16 As[64][136];      // padded; reused as fp16 store-stage
    __shared__ _Float16 Bs[128 * 128];    // XOR-swizzled 8-elem groups
    __shared__ float als_s[4][64];
    __shared__ float ald_s[4][64];
    const int tid = threadIdx.x;
    const int row0 = blockIdx.x * 64;

    if (SRC_F32) {
        const float* X = (const float*)Xsrc;
        for (int i = 0; i < 8; ++i) {
            int idx = tid + i * 256;
            int r = idx >> 5, q = idx & 31;
            int gr = row0 + r;
            float4 v = make_float4(0.f, 0.f, 0.f, 0.f);
            if (gr < N_NODES) v = ((const float4*)X)[(size_t)gr * 32 + q];
            half2t p0 = { (_Float16)v.x, (_Float16)v.y };
            half2t p1 = { (_Float16)v.z, (_Float16)v.w };
            *(half2t*)&As[r][q * 4]     = p0;
            *(half2t*)&As[r][q * 4 + 2] = p1;
        }
    } else {
        const uint4* X = (const uint4*)Xsrc;
        for (int i = 0; i < 4; ++i) {
            int idx = tid + i * 256;
            int r = idx >> 4, q = idx & 15;
            int gr = row0 + r;
            uint4 v = make_uint4(0u, 0u, 0u, 0u);
            if (gr < N_NODES) v = X[(size_t)gr * 16 + q];
            *(uint4*)&As[r][q * 8] = v;
        }
    }
    for (int i = 0; i < 8; ++i) {
        int idx = tid + i * 256;
        int r = idx >> 4, q = idx & 15;
        *(uint4*)&Bs[r * 128 + ((q ^ (r & 15)) << 3)] = ((const uint4*)Wt)[r * 16 + q];
    }
    __syncthreads();

    const int l = tid & 63, wv = tid >> 6;
    const int c0w = wv * 32;
    const int lr = l & 15, lq = l >> 4;

    floatx4 acc[4][2];
#pragma unroll
    for (int m = 0; m < 4; ++m)
#pragma unroll
        for (int n = 0; n < 2; ++n) acc[m][n] = (floatx4){0.f, 0.f, 0.f, 0.f};

#pragma unroll
    for (int kk = 0; kk < 4; ++kk) {
        int kb = kk * 32 + lq * 8;
        int kg = (kk * 4 + lq) ^ lr;
        half8 a0 = *(const half8*)&As[lr][kb];
        half8 a1 = *(const half8*)&As[16 + lr][kb];
        half8 a2 = *(const half8*)&As[32 + lr][kb];
        half8 a3 = *(const half8*)&As[48 + lr][kb];
        half8 b0 = *(const half8*)&Bs[(c0w + lr) * 128 + (kg << 3)];
        half8 b1 = *(const half8*)&Bs[(c0w + 16 + lr) * 128 + (kg << 3)];
        acc[0][0] = __builtin_amdgcn_mfma_f32_16x16x32_f16(a0, b0, acc[0][0], 0, 0, 0);
        acc[1][0] = __builtin_amdgcn_mfma_f32_16x16x32_f16(a1, b0, acc[1][0], 0, 0, 0);
        acc[2][0] = __builtin_amdgcn_mfma_f32_16x16x32_f16(a2, b0, acc[2][0], 0, 0, 0);
        acc[3][0] = __builtin_amdgcn_mfma_f32_16x16x32_f16(a3, b0, acc[3][0], 0, 0, 0);
        acc[0][1] = __builtin_amdgcn_mfma_f32_16x16x32_f16(a0, b1, acc[0][1], 0, 0, 0);
        acc[1][1] = __builtin_amdgcn_mfma_f32_16x16x32_f16(a1, b1, acc[1][1], 0, 0, 0);
        acc[2][1] = __builtin_amdgcn_mfma_f32_16x16x32_f16(a2, b1, acc[2][1], 0, 0, 0);
        acc[3][1] = __builtin_amdgcn_mfma_f32_16x16x32_f16(a3, b1, acc[3][1], 0, 0, 0);
    }

    __syncthreads();   // reuse As as store stage

    float asv0 = as_[c0w + lr],      adv0 = ad_[c0w + lr];
    float asv1 = as_[c0w + 16 + lr], adv1 = ad_[c0w + 16 + lr];
#pragma unroll
    for (int m = 0; m < 4; ++m) {
#pragma unroll
        for (int reg = 0; reg < 4; ++reg) {
            float v0 = acc[m][0][reg];
            float v1 = acc[m][1][reg];
            int rl = 16 * m + 4 * lq + reg;
            _Float16* rowp = &As[rl][0];
            rowp[c0w + lr]      = (_Float16)v0;
            rowp[c0w + 16 + lr] = (_Float16)v1;
            float ss = v0 * asv0 + v1 * asv1;
            float dd = v0 * adv0 + v1 * adv1;
            ss += __shfl_xor(ss, 1); dd += __shfl_xor(dd, 1);
            ss += __shfl_xor(ss, 2); dd += __shfl_xor(dd, 2);
            ss += __shfl_xor(ss, 4); dd += __shfl_xor(dd, 4);
            ss += __shfl_xor(ss, 8); dd += __shfl_xor(dd, 8);
            if (lr == 0) { als_s[wv][rl] = ss; ald_s[wv][rl] = dd; }
        }
    }
    __syncthreads();

    // coalesced fp16 H stores: 64 rows x 16 uint4
    for (int i = 0; i < 4; ++i) {
        int idx = tid + i * 256;
        int r = idx >> 4, q = idx & 15;
        int grow = row0 + r;
        if (grow < N_NODES) {
            uint4 v = *(uint4*)((unsigned short*)&As[r][0] + q * 8);
            ((uint4*)Hb)[(size_t)grow * 16 + q] = v;
        }
    }
    int r = tid & 63, sel = tid >> 6;
    int grow = row0 + r;
    if (grow < N_NODES) {
        if (sel == 0)      als[grow * 2 + 0] = als_s[0][r] + als_s[1][r];
        else if (sel == 1) als[grow * 2 + 1] = als_s[2][r] + als_s[3][r];
        else if (sel == 2) ald[grow * 2 + 0] = ald_s[0][r] + ald_s[1][r];
        else               ald[grow * 2 + 1] = ald_s[2][r] + ald_s[3][r];
    }
}

// ---------------- per-node softmax + aggregation ----------------
// softmax: lane j owns edge j. gather: 16-lane groups, 4 edges/iter via LDS (s,w0,w1) broadcast.
__global__ __launch_bounds__(256) void agg_kernel(const uint4* __restrict__ Hb4,
                                                  const uint2* __restrict__ csr2,
                                                  const float* __restrict__ als,
                                                  const float* __restrict__ ald,
                                                  const int* __restrict__ rowstart,
                                                  const float* __restrict__ bias,
                                                  _Float16* __restrict__ outp) {
    __shared__ uint4 sw[4][64];
    const int wv = threadIdx.x >> 6;
    int n = blockIdx.x * 4 + wv;
    if (n >= N_NODES) return;
    const int lane = threadIdx.x & 63;
    int start = rowstart[n], end = rowstart[n + 1];
    int deg = end - start;
    const float2* als2 = (const float2*)als;
    float2 adn = ((const float2*)ald)[n];

    // lane j resolves edge j
    int   s_reg  = n;
    float nq_reg = 0.f, a0_reg = -1e30f, a1_reg = -1e30f;
    if (lane < deg) {
        uint2 v = csr2[start + lane];
        s_reg  = (int)v.x;
        nq_reg = __uint_as_float(v.y);
        float2 av = als2[s_reg];
        float a0 = av.x + adn.x; a0_reg = (a0 > 0.f) ? a0 : NEG * a0;
        float a1 = av.y + adn.y; a1_reg = (a1 > 0.f) ? a1 : NEG * a1;
    }
    // per-node max (lane-parallel; rare stride loop for deg>64)
    float m0 = a0_reg, m1 = a1_reg;
    for (int i = start + 64 + lane; i < end; i += 64) {
        uint2 v = csr2[i];
        float2 av = als2[v.x];
        float a0 = av.x + adn.x; a0 = (a0 > 0.f) ? a0 : NEG * a0;
        float a1 = av.y + adn.y; a1 = (a1 > 0.f) ? a1 : NEG * a1;
        m0 = fmaxf(m0, a0); m1 = fmaxf(m1, a1);
    }
    for (int o = 32; o; o >>= 1) { m0 = fmaxf(m0, __shfl_xor(m0, o)); m1 = fmaxf(m1, __shfl_xor(m1, o)); }

    float e0 = __expf(a0_reg - m0), e1 = __expf(a1_reg - m1);
    float s0 = e0, s1 = e1;
    for (int i = start + 64 + lane; i < end; i += 64) {
        uint2 v = csr2[i];
        float2 av = als2[v.x];
        float a0 = av.x + adn.x; a0 = (a0 > 0.f) ? a0 : NEG * a0;
        float a1 = av.y + adn.y; a1 = (a1 > 0.f) ? a1 : NEG * a1;
        s0 += __expf(a0 - m0); s1 += __expf(a1 - m1);
    }
    for (int o = 32; o; o >>= 1) { s0 += __shfl_xor(s0, o); s1 += __shfl_xor(s1, o); }
    float inv0 = 1.f / (s0 + 1e-16f), inv1 = 1.f / (s1 + 1e-16f);

    // stash (s, w0, w1); lanes >= deg have nq_reg=0 -> w=0, s=n (safe row)
    sw[wv][lane] = make_uint4((unsigned)s_reg,
                              __float_as_uint(nq_reg * e0 * inv0),
                              __float_as_uint(nq_reg * e1 * inv1), 0u);

    const int  c16   = lane & 15;      // uint4 column: channels 8*c16 .. 8*c16+7
    const int  g     = lane >> 4;      // edge group
    const bool head0 = (c16 < 8);
    float acc0 = 0.f, acc1 = 0.f, acc2 = 0.f, acc3 = 0.f;
    float acc4 = 0.f, acc5 = 0.f, acc6 = 0.f, acc7 = 0.f;
    int cnt4 = (deg < 64) ? ((deg + 3) & ~3) : 64;
#pragma unroll 4
    for (int jp = 0; jp < cnt4; jp += 4) {
        uint4 sv = sw[wv][jp + g];
        float w  = __uint_as_float(head0 ? sv.y : sv.z);
        uint4 hv = Hb4[(size_t)(sv.x * 16u + (unsigned)c16)];
        half2t h0 = h2bits(hv.x), h1 = h2bits(hv.y), h2 = h2bits(hv.z), h3 = h2bits(hv.w);
        acc0 += (float)h0.x * w; acc1 += (float)h0.y * w;
        acc2 += (float)h1.x * w; acc3 += (float)h1.y * w;
        acc4 += (float)h2.x * w; acc5 += (float)h2.y * w;
        acc6 += (float)h3.x * w; acc7 += (float)h3.y * w;
    }
    // rare deg>64: process remaining chunks of 64
    for (int cbase = start + 64; cbase < end; cbase += 64) {
        int   s2 = n; float w0f = 0.f, w1f = 0.f;
        int i = cbase + lane;
        if (i < end) {
            uint2 v = csr2[i];
            s2 = (int)v.x;
            float nq = __uint_as_float(v.y);
            float2 av = als2[s2];
            float a0 = av.x + adn.x; a0 = (a0 > 0.f) ? a0 : NEG * a0;
            float a1 = av.y + adn.y; a1 = (a1 > 0.f) ? a1 : NEG * a1;
            w0f = nq * __expf(a0 - m0) * inv0;
            w1f = nq * __expf(a1 - m1) * inv1;
        }
        sw[wv][lane] = make_uint4((unsigned)s2, __float_as_uint(w0f), __float_as_uint(w1f), 0u);
        int rem = end - cbase; if (rem > 64) rem = 64;
        int r4 = (rem + 3) & ~3;
        for (int jp = 0; jp < r4; jp += 4) {
            uint4 sv = sw[wv][jp + g];
            float w  = __uint_as_float(head0 ? sv.y : sv.z);
            uint4 hv = Hb4[(size_t)(sv.x * 16u + (unsigned)c16)];
            half2t h0 = h2bits(hv.x), h1 = h2bits(hv.y), h2 = h2bits(hv.z), h3 = h2bits(hv.w);
            acc0 += (float)h0.x * w; acc1 += (float)h0.y * w;
            acc2 += (float)h1.x * w; acc3 += (float)h1.y * w;
            acc4 += (float)h2.x * w; acc5 += (float)h2.y * w;
            acc6 += (float)h3.x * w; acc7 += (float)h3.y * w;
        }
    }
    // reduce across the 4 edge groups
    acc0 += __shfl_xor(acc0, 16); acc1 += __shfl_xor(acc1, 16);
    acc2 += __shfl_xor(acc2, 16); acc3 += __shfl_xor(acc3, 16);
    acc4 += __shfl_xor(acc4, 16); acc5 += __shfl_xor(acc5, 16);
    acc6 += __shfl_xor(acc6, 16); acc7 += __shfl_xor(acc7, 16);
    acc0 += __shfl_xor(acc0, 32); acc1 += __shfl_xor(acc1, 32);
    acc2 += __shfl_xor(acc2, 32); acc3 += __shfl_xor(acc3, 32);
    acc4 += __shfl_xor(acc4, 32); acc5 += __shfl_xor(acc5, 32);
    acc6 += __shfl_xor(acc6, 32); acc7 += __shfl_xor(acc7, 32);

    if (g == 0) {
        float4 ba = ((const float4*)bias)[c16 * 2];
        float4 bb = ((const float4*)bias)[c16 * 2 + 1];
        float o0 = acc0 + ba.x; o0 = o0 > 0.f ? o0 : 0.f;
        float o1 = acc1 + ba.y; o1 = o1 > 0.f ? o1 : 0.f;
        float o2 = acc2 + ba.z; o2 = o2 > 0.f ? o2 : 0.f;
        float o3 = acc3 + ba.w; o3 = o3 > 0.f ? o3 : 0.f;
        float o4 = acc4 + bb.x; o4 = o4 > 0.f ? o4 : 0.f;
        float o5 = acc5 + bb.y; o5 = o5 > 0.f ? o5 : 0.f;
        float o6 = acc6 + bb.z; o6 = o6 > 0.f ? o6 : 0.f;
        float o7 = acc7 + bb.w; o7 = o7 > 0.f ? o7 : 0.f;
        half8 hv = { (_Float16)o0, (_Float16)o1, (_Float16)o2, (_Float16)o3,
                     (_Float16)o4, (_Float16)o5, (_Float16)o6, (_Float16)o7 };
        *(half8*)(outp + (size_t)n * 128 + 8 * c16) = hv;
    }
}

// ---------------- global mean pool: chunked partial sums + atomics ----------------
__global__ __launch_bounds__(256) void pool_partial(const half2t* __restrict__ Obh,
                                                    const int* __restrict__ batch,
                                                    float* __restrict__ sums) {
    int row0 = blockIdx.x * PCH;
    int c2 = threadIdx.x & 63;   // half2 column: channels 2c2, 2c2+1
    int r4 = threadIdx.x >> 6;   // 0..3 row phase
    int end = row0 + PCH; if (end > N_NODES) end = N_NODES;
    float a0 = 0.f, a1 = 0.f;
    int curg = -1;
    for (int i = row0 + r4; i < end; i += 4) {
        int g = batch[i];
        if (g != curg) {
            if (curg >= 0) {
                atomicAdd(&sums[curg * 128 + 2 * c2],     a0);
                atomicAdd(&sums[curg * 128 + 2 * c2 + 1], a1);
            }
            a0 = 0.f; a1 = 0.f; curg = g;
        }
        half2t hv = Obh[(size_t)i * 64 + c2];
        a0 += (float)hv.x;
        a1 += (float)hv.y;
    }
    if (curg >= 0) {
        atomicAdd(&sums[curg * 128 + 2 * c2],     a0);
        atomicAdd(&sums[curg * 128 + 2 * c2 + 1], a1);
    }
}

// ---------------- classifier: (sums/cnt) @ Wc + bc ----------------
__global__ void cls_kernel(const float* __restrict__ sums, const int* __restrict__ batch,
                           const float* __restrict__ Wc, const float* __restrict__ bc,
                           float* __restrict__ outp) {
    int g = blockIdx.x;
    __shared__ float p[128];
    __shared__ int cnt_s;
    if (threadIdx.x == 0) {
        int lo = 0, hi = N_NODES;
        while (lo < hi) { int mid = (lo + hi) >> 1; if (batch[mid] < g) lo = mid + 1; else hi = mid; }
        int start = lo;
        hi = N_NODES;
        while (lo < hi) { int mid = (lo + hi) >> 1; if (batch[mid] <= g) lo = mid + 1; else hi = mid; }
        cnt_s = lo - start;
    }
    __syncthreads();
    float inv = 1.f / fmaxf((float)cnt_s, 1.f);
    p[threadIdx.x] = sums[g * 128 + threadIdx.x] * inv;
    __syncthreads();
    if (threadIdx.x < 10) {
        float acc = bc[threadIdx.x];
        for (int k = 0; k < 128; ++k) acc += p[k] * Wc[k * 10 + threadIdx.x];
        outp[g * 10 + threadIdx.x] = acc;
    }
}

extern "C" void kernel_launch(void* const* d_in, const int* in_sizes, int n_in,
                              void* d_out, int out_size, void* d_ws, size_t ws_size,
                              hipStream_t stream) {
    const float* x     = (const float*)d_in[0];
    const int*   ei    = (const int*)d_in[1];
    const int*   batch = (const int*)d_in[2];
    const float* nc    = (const float*)d_in[3];
    const float* ec    = (const float*)d_in[4];
    const float* W0    = (const float*)d_in[5];
    const float* as0   = (const float*)d_in[6];
    const float* ad0   = (const float*)d_in[7];
    const float* b0    = (const float*)d_in[8];
    const float* W1    = (const float*)d_in[9];
    const float* as1   = (const float*)d_in[10];
    const float* ad1   = (const float*)d_in[11];
    const float* b1    = (const float*)d_in[12];
    const float* Wc    = (const float*)d_in[13];
    const float* bc    = (const float*)d_in[14];
    float* out = (float*)d_out;

    char* ws = (char*)d_ws;
    size_t off = 0;
    auto alloc = [&](size_t bytes) { void* p = ws + off; off += (bytes + 255) & ~size_t(255); return p; };
    unsigned*  Hb       = (unsigned*)alloc(sizeof(unsigned) * N_NODES * 64);    // fp16 H (pre-attn)
    _Float16*  Xh       = (_Float16*)alloc(sizeof(_Float16) * N_NODES * 128);   // fp16 layer-1 input
    _Float16*  Ob       = (_Float16*)alloc(sizeof(_Float16) * N_NODES * 128);   // fp16 layer-1 output
    float*     als      = (float*)alloc(sizeof(float) * N_NODES * 2);
    float*     ald      = (float*)alloc(sizeof(float) * N_NODES * 2);
    _Float16*  Wt0      = (_Float16*)alloc(sizeof(_Float16) * 128 * 128);
    _Float16*  Wt1      = (_Float16*)alloc(sizeof(_Float16) * 128 * 128);
    int*       deg      = (int*)alloc(sizeof(int) * N_NODES);
    int*       rank     = (int*)alloc(sizeof(int) * EA);
    int*       part     = (int*)alloc(sizeof(int) * NB_SCAN);
    int*       rowstart = (int*)alloc(sizeof(int) * (N_NODES + 1));
    uint2*     csr2     = (uint2*)alloc(sizeof(uint2) * EA);
    float*     sums     = (float*)alloc(sizeof(float) * NG * 128);

    init_kernel<<<NB_SCAN, 256, 0, stream>>>(W0, W1, Wt0, Wt1, deg, sums);
    hist_kernel<<<(EA + 255) / 256, 256, 0, stream>>>(ei, deg, rank);
    partial_kernel<<<NB_SCAN, 256, 0, stream>>>(deg, part);
    rowstart_kernel<<<NB_SCAN, 256, 0, stream>>>(deg, part, rowstart);
    build_kernel<<<(EA + 255) / 256, 256, 0, stream>>>(ei, ec, nc, rowstart, rank, csr2);

    int gemm_grid   = (N_NODES + 63) / 64;            // 782
    int nwaveblocks = (N_NODES + 3) / 4;              // 12500

    // layer 0
    gemm_mfma<1><<<gemm_grid, 256, 0, stream>>>(x, Wt0, as0, ad0, Hb, als, ald);
    agg_kernel<<<nwaveblocks, 256, 0, stream>>>((const uint4*)Hb, csr2, als, ald, rowstart, b0, Xh);

    // layer 1
    gemm_mfma<0><<<gemm_grid, 256, 0, stream>>>(Xh, Wt1, as1, ad1, Hb, als, ald);
    agg_kernel<<<nwaveblocks, 256, 0, stream>>>((const uint4*)Hb, csr2, als, ald, rowstart, b1, Ob);

    // pool (chunked partials) + classifier
    pool_partial<<<(N_NODES + PCH - 1) / PCH, 256, 0, stream>>>((const half2t*)Ob, batch, sums);
    cls_kernel<<<NG, 128, 0, stream>>>(sums, batch, Wc, bc, out);
}